// Round 3
// baseline (6875.085 us; speedup 1.0000x reference)
//
#include <hip/hip_runtime.h>
#include <stdint.h>

// Problem constants
#define H2      1024          // 2*H
#define TSTEPS  2000
#define TC_C    0.01f

// Topology: 8 groups x 8 WGs; 4 batches/group; 128 rows/WG (16 rows/wave,
// full K per wave); 512 thr (8 waves).
#define NGROUPS   8
#define WG_PER_G  8
#define BPG       4
#define ROWS_WG   128
#define NTHR      512
#define NBLOCKS   (NGROUPS * WG_PER_G)   // 64

// Output layout (fp32 elements): hn_last | rnn_out | x_last | x_out
#define OFF_RNN   32768
#define OFF_XL    (32768 + 65536000)
#define OFF_XO    (OFF_XL + 32768)

// ws layout: buf64 uint64[2][32][512] (256 KB). Each entry: low32 = packed
// bf16 pair of h[2cp],h[2cp+1]; high32 = step tag (h(s) carries tag s).
// No separate flags -- consumers poll the data words directly.

typedef __attribute__((ext_vector_type(8))) short bf16x8;
typedef __attribute__((ext_vector_type(4))) float f32x4;

__device__ __forceinline__ float clip01(float w) {
  return fminf(fmaxf(w, 1e-15f), 1.0f);
}
// round-to-nearest-even fp32 -> bf16 (low 16 bits of result)
__device__ __forceinline__ uint32_t f2bf(float x) {
  uint32_t u = __float_as_uint(x);
  return ((u + 0x7fffu + ((u >> 16) & 1u)) >> 16) & 0xffffu;
}

// ---------------------------------------------------------------------------
// Init: x_out/x_last broadcast, tagged bf16 h(0) into buf[0], buf[1] tags=-1.
// 256 blocks x 256 threads. Runs stream-ordered before the RNN kernel on
// every launch/replay -> tags are re-seeded each call (replay-safe).
// ---------------------------------------------------------------------------
__global__ void stralm_init_kernel(const float* __restrict__ hn,
                                   const float* __restrict__ x,
                                   float* __restrict__ out,
                                   float* __restrict__ ws) {
  const int tid = blockIdx.x * 256 + threadIdx.x;   // 0..65535
  const int b  = tid >> 11;
  const int r  = tid & 2047;
  const int jq = (r & 255) * 4;
  const int t0 = (r >> 8) * 250;
  const float4 xv = *(const float4*)(x + b * H2 + jq);
  float* xo = out + OFF_XO;
  for (int i = 0; i < 250; ++i) {
    const int t = t0 + i;
    *(float4*)(xo + (size_t)(b * TSTEPS + t) * H2 + jq) = xv;
  }
  uint64_t* buf64 = (uint64_t*)ws;
  if (tid < 16384) {   // one exchange entry each (2 h values)
    const float2 hv = *(const float2*)(hn + tid * 2);
    buf64[tid]         = (uint64_t)(f2bf(hv.x) | (f2bf(hv.y) << 16)); // tag 0
    buf64[16384 + tid] = 0xFFFFFFFF00000000ULL;                       // tag -1
  }
  if (tid < 8192)
    *(float4*)(out + OFF_XL + tid * 4) = *(const float4*)(x + tid * 4);
}

// ---------------------------------------------------------------------------
// Persistent RNN kernel. grid = 64, block = 512.
// ---------------------------------------------------------------------------
__global__ __launch_bounds__(NTHR, 1) void stralm_rnn_kernel(
    const float* __restrict__ inp,      // [B][T][4]
    const float* __restrict__ hn,       // [1][B][2H] fp32 h(0)
    const float* __restrict__ inhib,    // [B][T][2H]
    const float* __restrict__ ss_w, const float* __restrict__ a2a_w,
    const float* __restrict__ a2s_w, const float* __restrict__ s2a_w,
    const float* __restrict__ iw,       // [4][2H]
    const float* __restrict__ ss_fix, const float* __restrict__ ss_mask,
    const float* __restrict__ a2s_mask, const float* __restrict__ sign_v,
    const float* __restrict__ d1mask,
    float* __restrict__ out, float* __restrict__ ws) {
  // smem: init-phase wstage ushort[16][1032] (33024 B);
  //       loop-phase h_lds uint[2][4][516] double-buffered (16512 B)
  __shared__ __align__(16) uint32_t smem[8256];

  const int tid = threadIdx.x;
  const int g   = blockIdx.x & 7;    // group (heuristically XCD-local; only
                                     // a perf hint -- correctness is agent-scope)
  const int wg  = blockIdx.x >> 3;   // 0..7
  const int r0  = wg * ROWS_WG;
  const int l   = tid & 63;
  const int wv  = tid >> 6;          // wave 0..7 = 16-row slice, full K

  uint64_t* buf64 = (uint64_t*)ws;   // [2][32][512]

  // ---- Build this wave's 16 W_rec rows as bf16 MFMA A-frags (full K) -----
  // A-frag (16x16x32): lane supplies A[m = l&15][k = kt*32 + (l>>4)*8 + j].
  bf16x8 afr[32];
  {
    unsigned short* wstage = (unsigned short*)smem;  // [16][1032]
    for (int mt = 0; mt < 8; ++mt) {
      __syncthreads();
      for (int i = 0; i < 32; ++i) {
        const int idx = i * NTHR + tid;        // 16*1024
        const int jt  = idx >> 10;
        const int k   = idx & 1023;
        const int jg  = r0 + mt * 16 + jt;
        const int jq  = jg & 511;
        float w;
        if (jg < 512) {
          if (k < 512)
            w = -(ss_mask[jq * 512 + k] * clip01(ss_w[jq * 512 + k]) +
                  ss_fix[jq * 512 + k]);
          else {
            const int kk = k - 512;
            w = a2s_mask[jq * 512 + kk] * clip01(a2s_w[jq * 512 + kk]);
          }
        } else {
          if (k < 512)
            w = clip01(s2a_w[jq * 512 + k]);
          else {
            const int kk = k - 512;
            w = clip01(a2a_w[jq * 512 + kk]) * sign_v[kk];
          }
        }
        wstage[jt * 1032 + k] = (unsigned short)f2bf(w);
      }
      __syncthreads();
      if (wv == mt) {
#pragma unroll
        for (int kt = 0; kt < 32; ++kt)
          afr[kt] = *(const bf16x8*)&wstage[(l & 15) * 1032 + kt * 32 +
                                            (l >> 4) * 8];
      }
    }
  }
  __syncthreads();

  uint32_t* h_lds = smem;            // [2][4][516] bf16-pairs, double-buffered

  // ---- per-lane epilogue state: lanes with (l&15)<4 own 4 rows x 1 batch --
  const int  n    = l & 15;          // MFMA D column = batch-in-group
  const bool act  = (n < 4);
  const int  bg   = g * BPG + (act ? n : 0);
  const int  grow = r0 + wv * 16 + (l >> 4) * 4;   // 4 consecutive rows
  float4 iwr0 = {}, iwr1 = {}, iwr2 = {}, iwr3 = {}, dmr = {}, hold = {};
  float4 inh_cur = {}, ip_cur = {};
  if (act) {
    iwr0 = *(const float4*)(iw + 0 * H2 + grow);
    iwr1 = *(const float4*)(iw + 1 * H2 + grow);
    iwr2 = *(const float4*)(iw + 2 * H2 + grow);
    iwr3 = *(const float4*)(iw + 3 * H2 + grow);
    dmr  = *(const float4*)(d1mask + grow);
    hold = *(const float4*)(hn + bg * H2 + grow);
    inh_cur = *(const float4*)(inhib + (size_t)bg * TSTEPS * H2 + grow);
    ip_cur  = *(const float4*)(inp + bg * (TSTEPS * 4));
  }
  const int bb = l & 3;              // batch whose h this lane feeds as B-frag

  for (int t = 0; t < TSTEPS; ++t) {
    const int p = t & 1;
    // ---- poll h(t) (tag >= t) and stage to LDS; 4 entries per thread ----
    const uint64_t* src = buf64 + p * 16384 + g * 2048 + tid;
    uint32_t* dst = h_lds + p * 2064 + tid;
#pragma unroll
    for (int j = 0; j < 4; ++j) {
      uint64_t v = __hip_atomic_load(src + j * 512, __ATOMIC_RELAXED,
                                     __HIP_MEMORY_SCOPE_AGENT);
      while ((int)(v >> 32) < t) {
        __builtin_amdgcn_s_sleep(1);
        v = __hip_atomic_load(src + j * 512, __ATOMIC_RELAXED,
                              __HIP_MEMORY_SCOPE_AGENT);
      }
      dst[j * 516] = (uint32_t)v;
    }
    __syncthreads();

    // ---- B-frags from LDS + 32 MFMA (full K=1024, rows wv*16..+15) ----
    const unsigned short* hs =
        (const unsigned short*)h_lds + p * 4128 + bb * 1032 + (l >> 4) * 8;
    f32x4 acc = {0.f, 0.f, 0.f, 0.f};
#pragma unroll
    for (int kt = 0; kt < 32; ++kt) {
      const bf16x8 bfr = *(const bf16x8*)&hs[kt * 32];
      acc = __builtin_amdgcn_mfma_f32_16x16x32_bf16(afr[kt], bfr, acc, 0, 0, 0);
    }

    // ---- epilogue: acc[q] is the complete dot for row grow+q, batch n ----
    if (act) {
      const float d0 = dmr.x * (iwr0.x * ip_cur.x + iwr1.x * ip_cur.y +
                                iwr2.x * ip_cur.z + iwr3.x * ip_cur.w) + inh_cur.x;
      const float d1 = dmr.y * (iwr0.y * ip_cur.x + iwr1.y * ip_cur.y +
                                iwr2.y * ip_cur.z + iwr3.y * ip_cur.w) + inh_cur.y;
      const float d2 = dmr.z * (iwr0.z * ip_cur.x + iwr1.z * ip_cur.y +
                                iwr2.z * ip_cur.z + iwr3.z * ip_cur.w) + inh_cur.z;
      const float d3 = dmr.w * (iwr0.w * ip_cur.x + iwr1.w * ip_cur.y +
                                iwr2.w * ip_cur.z + iwr3.w * ip_cur.w) + inh_cur.w;
      const float h0 = fmaxf(0.f, (1.f - TC_C) * hold.x + TC_C * (acc[0] + d0));
      const float h1 = fmaxf(0.f, (1.f - TC_C) * hold.y + TC_C * (acc[1] + d1));
      const float h2 = fmaxf(0.f, (1.f - TC_C) * hold.z + TC_C * (acc[2] + d2));
      const float h3 = fmaxf(0.f, (1.f - TC_C) * hold.w + TC_C * (acc[3] + d3));
      hold = (float4){h0, h1, h2, h3};
      // tagged exchange stores FIRST (critical path)
      const uint64_t tagv = ((uint64_t)(uint32_t)(t + 1)) << 32;
      uint64_t* ep = buf64 + (p ^ 1) * 16384 + bg * 512 + (grow >> 1);
      __hip_atomic_store(ep, tagv | (uint64_t)(f2bf(h0) | (f2bf(h1) << 16)),
                         __ATOMIC_RELAXED, __HIP_MEMORY_SCOPE_AGENT);
      __hip_atomic_store(ep + 1, tagv | (uint64_t)(f2bf(h2) | (f2bf(h3) << 16)),
                         __ATOMIC_RELAXED, __HIP_MEMORY_SCOPE_AGENT);
      // rnn_out
      const f32x4 hv4 = {h0, h1, h2, h3};
      __builtin_nontemporal_store(
          hv4, (f32x4*)(out + OFF_RNN + (size_t)bg * (TSTEPS * H2) +
                        (size_t)t * H2 + grow));
      if (t == TSTEPS - 1)
        *(float4*)(out + bg * H2 + grow) = (float4){h0, h1, h2, h3};
      // prefetch next step's drive inputs (a full step of latency to land)
      const int tn = (t < TSTEPS - 1) ? t + 1 : TSTEPS - 1;
      inh_cur = *(const float4*)(inhib + ((size_t)bg * TSTEPS + tn) * H2 + grow);
      ip_cur  = *(const float4*)(inp + bg * (TSTEPS * 4) + tn * 4);
    }
    // no trailing barrier: h_lds is double-buffered and the tag dependency
    // chain guarantees no WG/wave can re-enter a buffer while it's read.
  }
}

// ---------------------------------------------------------------------------
extern "C" void kernel_launch(void* const* d_in, const int* in_sizes, int n_in,
                              void* d_out, int out_size, void* d_ws,
                              size_t ws_size, hipStream_t stream) {
  const float* inp      = (const float*)d_in[0];
  const float* hn       = (const float*)d_in[1];
  const float* x        = (const float*)d_in[2];
  const float* inhib    = (const float*)d_in[3];
  const float* ss_w     = (const float*)d_in[4];
  const float* a2a_w    = (const float*)d_in[5];
  const float* a2s_w    = (const float*)d_in[6];
  const float* s2a_w    = (const float*)d_in[7];
  const float* iw       = (const float*)d_in[8];
  const float* ss_fix   = (const float*)d_in[9];
  const float* ss_mask  = (const float*)d_in[10];
  const float* a2s_mask = (const float*)d_in[11];
  const float* sign_v   = (const float*)d_in[12];
  const float* d1mask   = (const float*)d_in[13];
  float* out = (float*)d_out;
  float* ws  = (float*)d_ws;

  hipLaunchKernelGGL(stralm_init_kernel, dim3(256), dim3(256), 0, stream,
                     hn, x, out, ws);
  hipLaunchKernelGGL(stralm_rnn_kernel, dim3(NBLOCKS), dim3(NTHR), 0, stream,
                     inp, hn, inhib, ss_w, a2a_w, a2s_w, s2a_w, iw, ss_fix,
                     ss_mask, a2s_mask, sign_v, d1mask, out, ws);
}

// Round 4
// 4764.352 us; speedup vs baseline: 1.4430x; 1.4430x over previous
//
#include <hip/hip_runtime.h>
#include <stdint.h>

// Problem constants
#define H2      1024          // 2*H
#define TSTEPS  2000
#define TC_C    0.01f

// Topology: 8 groups x 8 WGs; 4 batches/group; 128 rows/WG (16 rows/wave,
// full K per wave); 512 thr (8 waves).
#define NGROUPS   8
#define WG_PER_G  8
#define BPG       4
#define ROWS_WG   128
#define NTHR      512
#define NBLOCKS   (NGROUPS * WG_PER_G)   // 64

// Output layout (fp32 elements): hn_last | rnn_out | x_last | x_out
#define OFF_RNN   32768
#define OFF_XL    (32768 + 65536000)
#define OFF_XO    (OFF_XL + 32768)

// ws layout: buf32 uint32[2][32][512] (packed bf16-pair h exchange, 128 KB)
// at 0; flags int[8][16] at int-offset 32768 (64B per group).
#define FLAG_BASE 32768

// LDS h staging: per buffer 4 batches x 520 uint32 (pad 512->520 so B-frag
// ds_read_b128 banks are (8*bb + 4*h4) mod 32 -> uniform 2-way = free).
#define HPAD 520

typedef __attribute__((ext_vector_type(8))) short bf16x8;
typedef __attribute__((ext_vector_type(4))) float f32x4;

__device__ __forceinline__ float clip01(float w) {
  return fminf(fmaxf(w, 1e-15f), 1.0f);
}
// round-to-nearest-even fp32 -> bf16 (low 16 bits of result)
__device__ __forceinline__ uint32_t f2bf(float x) {
  uint32_t u = __float_as_uint(x);
  return ((u + 0x7fffu + ((u >> 16) & 1u)) >> 16) & 0xffffu;
}

// ---------------------------------------------------------------------------
// Init: x_out/x_last broadcast, packed bf16 h(0) into buf[0], zero flags.
// 256 blocks x 256 threads. Stream-ordered before RNN kernel every replay.
// ---------------------------------------------------------------------------
__global__ void stralm_init_kernel(const float* __restrict__ hn,
                                   const float* __restrict__ x,
                                   float* __restrict__ out,
                                   float* __restrict__ ws) {
  const int tid = blockIdx.x * 256 + threadIdx.x;   // 0..65535
  const int b  = tid >> 11;
  const int r  = tid & 2047;
  const int jq = (r & 255) * 4;
  const int t0 = (r >> 8) * 250;
  const float4 xv = *(const float4*)(x + b * H2 + jq);
  float* xo = out + OFF_XO;
  for (int i = 0; i < 250; ++i) {
    const int t = t0 + i;
    *(float4*)(xo + (size_t)(b * TSTEPS + t) * H2 + jq) = xv;
  }
  uint32_t* buf32 = (uint32_t*)ws;
  if (tid < 16384) {   // one packed pair each
    const float2 hv = *(const float2*)(hn + tid * 2);
    buf32[tid] = f2bf(hv.x) | (f2bf(hv.y) << 16);
  }
  if (tid < 8192)
    *(float4*)(out + OFF_XL + tid * 4) = *(const float4*)(x + tid * 4);
  if (tid < 128) ((int*)ws)[FLAG_BASE + tid] = 0;
}

// ---------------------------------------------------------------------------
// Persistent RNN kernel. grid = 64, block = 512.
// ---------------------------------------------------------------------------
__global__ __launch_bounds__(NTHR, 1) void stralm_rnn_kernel(
    const float* __restrict__ inp,      // [B][T][4]
    const float* __restrict__ hn,       // [1][B][2H] fp32 h(0)
    const float* __restrict__ inhib,    // [B][T][2H]
    const float* __restrict__ ss_w, const float* __restrict__ a2a_w,
    const float* __restrict__ a2s_w, const float* __restrict__ s2a_w,
    const float* __restrict__ iw,       // [4][2H]
    const float* __restrict__ ss_fix, const float* __restrict__ ss_mask,
    const float* __restrict__ a2s_mask, const float* __restrict__ sign_v,
    const float* __restrict__ d1mask,
    float* __restrict__ out, float* __restrict__ ws) {
  // smem: init-phase wstage ushort[16][1032] (33024 B);
  //       loop-phase h_lds uint32[2][4][520] double-buffered (16640 B)
  __shared__ __align__(16) uint32_t smem[8256];

  const int tid = threadIdx.x;
  const int g   = blockIdx.x & 7;    // group (XCD-local heuristic, perf only)
  const int wg  = blockIdx.x >> 3;   // 0..7
  const int r0  = wg * ROWS_WG;
  const int l   = tid & 63;
  const int wv  = tid >> 6;          // wave 0..7 = 16-row slice, full K

  uint32_t* buf32 = (uint32_t*)ws;              // [2][32][512]
  int*      flags = (int*)ws + FLAG_BASE + g * 16;

  // ---- Build this wave's 16 W_rec rows as bf16 MFMA A-frags (full K) -----
  bf16x8 afr[32];
  {
    unsigned short* wstage = (unsigned short*)smem;  // [16][1032]
    for (int mt = 0; mt < 8; ++mt) {
      __syncthreads();
      for (int i = 0; i < 32; ++i) {
        const int idx = i * NTHR + tid;        // 16*1024
        const int jt  = idx >> 10;
        const int k   = idx & 1023;
        const int jg  = r0 + mt * 16 + jt;
        const int jq  = jg & 511;
        float w;
        if (jg < 512) {
          if (k < 512)
            w = -(ss_mask[jq * 512 + k] * clip01(ss_w[jq * 512 + k]) +
                  ss_fix[jq * 512 + k]);
          else {
            const int kk = k - 512;
            w = a2s_mask[jq * 512 + kk] * clip01(a2s_w[jq * 512 + kk]);
          }
        } else {
          if (k < 512)
            w = clip01(s2a_w[jq * 512 + k]);
          else {
            const int kk = k - 512;
            w = clip01(a2a_w[jq * 512 + kk]) * sign_v[kk];
          }
        }
        wstage[jt * 1032 + k] = (unsigned short)f2bf(w);
      }
      __syncthreads();
      if (wv == mt) {
#pragma unroll
        for (int kt = 0; kt < 32; ++kt)
          afr[kt] = *(const bf16x8*)&wstage[(l & 15) * 1032 + kt * 32 +
                                            (l >> 4) * 8];
      }
    }
  }
  __syncthreads();

  uint32_t* h_lds = smem;   // [2][4][HPAD] packed bf16 pairs, double-buffered

  // ---- per-lane epilogue state: lanes with (l&15)<4 own 4 rows x 1 batch --
  const int  n    = l & 15;          // MFMA D column = batch-in-group
  const bool act  = (n < 4);
  const int  h4   = l >> 4;
  const int  bg   = g * BPG + (act ? n : 0);
  const int  grow = r0 + wv * 16 + h4 * 4;    // 4 consecutive rows
  float4 iwr0 = {}, iwr1 = {}, iwr2 = {}, iwr3 = {}, dmr = {}, hold = {};
  float4 inh_cur = {}, ip_cur = {};
  if (act) {
    iwr0 = *(const float4*)(iw + 0 * H2 + grow);
    iwr1 = *(const float4*)(iw + 1 * H2 + grow);
    iwr2 = *(const float4*)(iw + 2 * H2 + grow);
    iwr3 = *(const float4*)(iw + 3 * H2 + grow);
    dmr  = *(const float4*)(d1mask + grow);
    hold = *(const float4*)(hn + bg * H2 + grow);
    inh_cur = *(const float4*)(inhib + (size_t)bg * TSTEPS * H2 + grow);
    ip_cur  = *(const float4*)(inp + bg * (TSTEPS * 4));
  }
  const int bb = l & 3;              // batch whose h this lane feeds as B-frag

  for (int t = 0; t < TSTEPS; ++t) {
    const int p = t & 1;
    // ---- wait for h(t): all 8 group flags >= t ----
    if (tid < WG_PER_G) {
      const int* fl = flags + tid;
      while (__hip_atomic_load(fl, __ATOMIC_RELAXED,
                               __HIP_MEMORY_SCOPE_AGENT) < t)
        __builtin_amdgcn_s_sleep(1);
    }
    __syncthreads();

    // ---- stage group h(t) from LLC -> LDS (2 x 8B per thread) ----
    {
      const uint64_t* src64 = (const uint64_t*)(buf32 + p * 16384 + g * 2048);
      const uint64_t v0 = __hip_atomic_load(src64 + tid, __ATOMIC_RELAXED,
                                            __HIP_MEMORY_SCOPE_AGENT);
      const uint64_t v1 = __hip_atomic_load(src64 + 512 + tid, __ATOMIC_RELAXED,
                                            __HIP_MEMORY_SCOPE_AGENT);
      uint32_t* hbuf = h_lds + p * (4 * HPAD);
      const int e0 = 2 * tid;            // entries e0, e0+1 (same batch)
      const int e1 = 1024 + 2 * tid;
      *(uint64_t*)(hbuf + (e0 >> 9) * HPAD + (e0 & 511)) = v0;
      *(uint64_t*)(hbuf + (e1 >> 9) * HPAD + (e1 & 511)) = v1;
    }
    __syncthreads();

    // ---- B-frags from padded LDS + 32 MFMA (full K=1024) ----
    const unsigned short* hs = (const unsigned short*)(h_lds + p * (4 * HPAD)) +
                               bb * (2 * HPAD) + h4 * 8;
    f32x4 acc = {0.f, 0.f, 0.f, 0.f};
#pragma unroll
    for (int kt = 0; kt < 32; ++kt) {
      const bf16x8 bfr = *(const bf16x8*)&hs[kt * 32];
      acc = __builtin_amdgcn_mfma_f32_16x16x32_bf16(afr[kt], bfr, acc, 0, 0, 0);
    }

    // ---- epilogue: acc[q] = full dot for row grow+q, batch n ----
    float h0 = 0.f, h1 = 0.f, h2 = 0.f, h3 = 0.f;
    if (act) {
      const float d0 = dmr.x * (iwr0.x * ip_cur.x + iwr1.x * ip_cur.y +
                                iwr2.x * ip_cur.z + iwr3.x * ip_cur.w) + inh_cur.x;
      const float d1 = dmr.y * (iwr0.y * ip_cur.x + iwr1.y * ip_cur.y +
                                iwr2.y * ip_cur.z + iwr3.y * ip_cur.w) + inh_cur.y;
      const float d2 = dmr.z * (iwr0.z * ip_cur.x + iwr1.z * ip_cur.y +
                                iwr2.z * ip_cur.z + iwr3.z * ip_cur.w) + inh_cur.z;
      const float d3 = dmr.w * (iwr0.w * ip_cur.x + iwr1.w * ip_cur.y +
                                iwr2.w * ip_cur.z + iwr3.w * ip_cur.w) + inh_cur.w;
      h0 = fmaxf(0.f, (1.f - TC_C) * hold.x + TC_C * (acc[0] + d0));
      h1 = fmaxf(0.f, (1.f - TC_C) * hold.y + TC_C * (acc[1] + d1));
      h2 = fmaxf(0.f, (1.f - TC_C) * hold.z + TC_C * (acc[2] + d2));
      h3 = fmaxf(0.f, (1.f - TC_C) * hold.w + TC_C * (acc[3] + d3));
      hold = (float4){h0, h1, h2, h3};
      // exchange store: one 8B packed store covering this lane's 4 rows
      const uint64_t pk2 = (uint64_t)(f2bf(h0) | (f2bf(h1) << 16)) |
                           ((uint64_t)(f2bf(h2) | (f2bf(h3) << 16)) << 32);
      uint64_t* ep = (uint64_t*)(buf32 + (p ^ 1) * 16384 + bg * 512) +
                     (grow >> 2);
      __hip_atomic_store(ep, pk2, __ATOMIC_RELAXED, __HIP_MEMORY_SCOPE_AGENT);
    }
    // drain exchange stores only, then publish flag
    asm volatile("s_waitcnt vmcnt(0)" ::: "memory");
    __syncthreads();
    if (tid == 0)
      __hip_atomic_store(flags + wg, t + 1, __ATOMIC_RELAXED,
                         __HIP_MEMORY_SCOPE_AGENT);
    // off-critical-path: rnn_out, hn_last, next-step input prefetch
    if (act) {
      const f32x4 hv4 = {h0, h1, h2, h3};
      __builtin_nontemporal_store(
          hv4, (f32x4*)(out + OFF_RNN + (size_t)bg * (TSTEPS * H2) +
                        (size_t)t * H2 + grow));
      if (t == TSTEPS - 1)
        *(float4*)(out + bg * H2 + grow) = (float4){h0, h1, h2, h3};
      const int tn = (t < TSTEPS - 1) ? t + 1 : TSTEPS - 1;
      inh_cur = *(const float4*)(inhib + ((size_t)bg * TSTEPS + tn) * H2 + grow);
      ip_cur  = *(const float4*)(inp + bg * (TSTEPS * 4) + tn * 4);
    }
  }
}

// ---------------------------------------------------------------------------
extern "C" void kernel_launch(void* const* d_in, const int* in_sizes, int n_in,
                              void* d_out, int out_size, void* d_ws,
                              size_t ws_size, hipStream_t stream) {
  const float* inp      = (const float*)d_in[0];
  const float* hn       = (const float*)d_in[1];
  const float* x        = (const float*)d_in[2];
  const float* inhib    = (const float*)d_in[3];
  const float* ss_w     = (const float*)d_in[4];
  const float* a2a_w    = (const float*)d_in[5];
  const float* a2s_w    = (const float*)d_in[6];
  const float* s2a_w    = (const float*)d_in[7];
  const float* iw       = (const float*)d_in[8];
  const float* ss_fix   = (const float*)d_in[9];
  const float* ss_mask  = (const float*)d_in[10];
  const float* a2s_mask = (const float*)d_in[11];
  const float* sign_v   = (const float*)d_in[12];
  const float* d1mask   = (const float*)d_in[13];
  float* out = (float*)d_out;
  float* ws  = (float*)d_ws;

  hipLaunchKernelGGL(stralm_init_kernel, dim3(256), dim3(256), 0, stream,
                     hn, x, out, ws);
  hipLaunchKernelGGL(stralm_rnn_kernel, dim3(NBLOCKS), dim3(NTHR), 0, stream,
                     inp, hn, inhib, ss_w, a2a_w, a2s_w, s2a_w, iw, ss_fix,
                     ss_mask, a2s_mask, sign_v, d1mask, out, ws);
}